// Round 13
// baseline (76.134 us; speedup 1.0000x reference)
//
#include <hip/hip_runtime.h>
#include <hip/hip_bf16.h>

// GroupAttention: split-kernel MFMA pipeline. B=256, N=80, C=256, H=8, hd=10.
// R9-proven configuration + vmcnt(0) hardening of the aliased-Q load drain.
// qkv_kernel (per b; Q pre-scaled by log2e; cpb fused into extra blocks)
// -> attn2_kernel (per (b,h); 4 waves x 64 c-rows; float4 bias via MFMA
// C-operand; hw exp2) -> proj_kernel2 (c-half, in-place safe).
// Q lives inside d_out (slot each attn block later overwrites).
// Fallback to fused mega_kernel if ws_size < 32MB+32KB.

#define B_SZ   256
#define N_TOK  80
#define C_CH   256
#define RPE_H  512
#define TBL_R  765
#define EPS_   5e-5f
#define L2E    1.44269504088896f

typedef __bf16 bf16x8 __attribute__((ext_vector_type(8)));
typedef float  f32x4  __attribute__((ext_vector_type(4)));
typedef unsigned long long ull;

__device__ inline unsigned int bfb(float f) {
    __hip_bfloat16 h = __float2bfloat16(f);
    return (unsigned int)reinterpret_cast<unsigned short&>(h);
}
__device__ inline float bf2f(unsigned short u) {
    unsigned int w = ((unsigned int)u) << 16;
    return __uint_as_float(w);
}
__device__ inline unsigned int cvtpk(float lo, float hi) {
    unsigned int r;
    asm("v_cvt_pk_bf16_f32 %0, %1, %2" : "=v"(r) : "v"(lo), "v"(hi));
    return r;
}
// hardware exp2 via builtin (compiler handles TRANS->VALU hazard; R7 lesson)
#if defined(__has_builtin) && __has_builtin(__builtin_amdgcn_exp2f)
__device__ inline float vexp2(float x) { return __builtin_amdgcn_exp2f(x); }
#else
__device__ inline float vexp2(float x) {
    float r;
    asm volatile("v_exp_f32 %0, %1\n\ts_nop 1" : "=v"(r) : "v"(x));
    return r;
}
#endif

// ---------------- Kernel 1 (fallback path only): CPB MLP ------------------------
__global__ __launch_bounds__(64) void cpb_kernel(const float* __restrict__ table,
                                                 const float* __restrict__ w1,
                                                 const float* __restrict__ b1,
                                                 const float* __restrict__ w2,
                                                 float* __restrict__ btT)
{
    int r = blockIdx.x;
    int l = threadIdx.x;
    float t0 = table[r * 2 + 0];
    float t1 = table[r * 2 + 1];
    float part[8];
#pragma unroll
    for (int h = 0; h < 8; ++h) part[h] = 0.f;
    for (int j = l; j < RPE_H; j += 64) {
        float hv = fmaf(t0, w1[j * 2 + 0], fmaf(t1, w1[j * 2 + 1], b1[j]));
        hv = fmaxf(hv, 0.f);
#pragma unroll
        for (int h = 0; h < 8; ++h)
            part[h] = fmaf(hv, w2[h * RPE_H + j], part[h]);
    }
#pragma unroll
    for (int h = 0; h < 8; ++h) {
#pragma unroll
        for (int off = 32; off > 0; off >>= 1)
            part[h] += __shfl_xor(part[h], off, 64);
    }
    if (l == 0) {
#pragma unroll
        for (int h = 0; h < 8; ++h)
            btT[h * TBL_R + r] = L2E * 16.f / (1.f + __expf(-part[h]));
    }
}

// ---------------- Kernel 2a: qkv GEMM per b (+ fused CPB blocks) --------------
// blocks 0..255: qkv for batch b. blocks 256..351: CPB rows (8 rows/block, 1/wave).
// Q (inside d_out) per (b,h) at ((b*80+h*10)*1024): [256 c][16 d] bf16, *log2e.
// K: ws per (b,h) 8192B [256 e][16 d]. V^T: ws per (b,h) 8192B [16 d][256 e],
// row d=10 = 1.0 (MFMA row-sum trick).
__global__ __launch_bounds__(512, 4) void qkv_kernel(const float* __restrict__ x,
                                                     const float* __restrict__ w_qkv,
                                                     const float* __restrict__ q_bias,
                                                     const float* __restrict__ v_bias,
                                                     const float* __restrict__ table,
                                                     const float* __restrict__ w1,
                                                     const float* __restrict__ b1,
                                                     const float* __restrict__ w2,
                                                     char* __restrict__ qout,
                                                     char* __restrict__ kbufc,
                                                     char* __restrict__ vbufc,
                                                     float* __restrict__ btT)
{
    __shared__ __align__(16) char smem[53248];   // Xs[256][104] bf16, stride 208B
    const int tid = threadIdx.x;
    const int lane = tid & 63, w = tid >> 6;
    const int g = lane >> 4, m = lane & 15;

    // ---- fused CPB blocks ----
    if (blockIdx.x >= 256) {
        int r = (blockIdx.x - 256) * 8 + w;
        if (r < TBL_R) {
            int l = lane;
            float t0 = table[r * 2 + 0];
            float t1 = table[r * 2 + 1];
            float part[8];
#pragma unroll
            for (int h = 0; h < 8; ++h) part[h] = 0.f;
            for (int j = l; j < RPE_H; j += 64) {
                float hv = fmaf(t0, w1[j * 2 + 0], fmaf(t1, w1[j * 2 + 1], b1[j]));
                hv = fmaxf(hv, 0.f);
#pragma unroll
                for (int h = 0; h < 8; ++h)
                    part[h] = fmaf(hv, w2[h * RPE_H + j], part[h]);
            }
#pragma unroll
            for (int h = 0; h < 8; ++h) {
#pragma unroll
                for (int off = 32; off > 0; off >>= 1)
                    part[h] += __shfl_xor(part[h], off, 64);
            }
            if (l == 0) {
#pragma unroll
                for (int h = 0; h < 8; ++h)
                    btT[h * TBL_R + r] = L2E * 16.f / (1.f + __expf(-part[h]));
            }
        }
        return;
    }

    const int b = blockIdx.x;
    bf16x8 zf;
#pragma unroll
    for (int i = 0; i < 8; ++i) zf[i] = (__bf16)0.0f;
    const f32x4 zacc = {0.f, 0.f, 0.f, 0.f};

    // stage Xs[c][n] bf16 (x transposed), zero-pad n=80..95
    {
        const float* xb = x + (size_t)b * (N_TOK * C_CH);
        for (int u = tid; u < 10240; u += 512) {
            int np = u >> 8, c = u & 255;
            float a0 = xb[(2 * np) * C_CH + c];
            float a1 = xb[(2 * np + 1) * C_CH + c];
            *(unsigned int*)(smem + c * 208 + np * 4) = bfb(a0) | (bfb(a1) << 16);
        }
        for (int u = tid; u < 2048; u += 512) {
            int c = u >> 3, np = u & 7;
            *(unsigned int*)(smem + c * 208 + 160 + np * 4) = 0u;
        }
    }
    __syncthreads();

    // each wave owns 3 of the 24 (s,h) tile-rows; all 16 c-tiles
#pragma unroll 1
    for (int i3 = 0; i3 < 3; ++i3) {
        const int sh = w * 3 + i3;          // 0..23
        const int s = sh >> 3, h = sh & 7;
        const float* wrow = w_qkv + (s * 80 + h * 10 + m) * 80;
        bf16x8 af[3];
#pragma unroll
        for (int ks = 0; ks < 3; ++ks) {
            bf16x8 f = zf;
            bool valid = (m < 10) && !(ks == 2 && g >= 2);
            if (valid) {
                const float* p = wrow + ks * 32 + g * 8;
                float4 l4 = *(const float4*)p;
                float4 h4 = *(const float4*)(p + 4);
                f[0] = (__bf16)l4.x; f[1] = (__bf16)l4.y; f[2] = (__bf16)l4.z; f[3] = (__bf16)l4.w;
                f[4] = (__bf16)h4.x; f[5] = (__bf16)h4.y; f[6] = (__bf16)h4.z; f[7] = (__bf16)h4.w;
            }
            af[ks] = f;
        }
        float bias_r[4];
#pragma unroll
        for (int r = 0; r < 4; ++r) {
            int dd = 4 * g + r;
            float bv = 0.f;
            if (dd < 10) {
                if (s == 0) bv = q_bias[h * 10 + dd];
                else if (s == 2) bv = v_bias[h * 10 + dd];
            }
            bias_r[r] = bv;
        }
        char* qb = qout + ((size_t)b * 80 + h * 10) * 1024;
        char* kb = kbufc + ((size_t)b * 8 + h) * 8192;
        char* vb = vbufc + ((size_t)b * 8 + h) * 8192;

#pragma unroll 2
        for (int ct = 0; ct < 16; ++ct) {
            f32x4 acc = zacc;
#pragma unroll
            for (int ks = 0; ks < 3; ++ks) {
                bf16x8 bfr = *(const bf16x8*)(smem + (16 * ct + m) * 208 + ks * 64 + g * 16);
                acc = __builtin_amdgcn_mfma_f32_16x16x32_bf16(af[ks], bfr, acc, 0, 0, 0);
            }
            int c = 16 * ct + m;
#pragma unroll
            for (int r = 0; r < 4; ++r) acc[r] += bias_r[r];
            if (s < 2) {
                float ss = acc[0]*acc[0] + acc[1]*acc[1] + acc[2]*acc[2] + acc[3]*acc[3];
                ss += __shfl_xor(ss, 16);
                ss += __shfl_xor(ss, 32);
                // Q gets log2(e) folded in so QK^T emerges pre-scaled for exp2
                float inv = ((s == 0) ? L2E : 1.f) / (sqrtf(ss) + EPS_);
                ull pk = (ull)bfb(acc[0] * inv) | ((ull)bfb(acc[1] * inv) << 16)
                       | ((ull)bfb(acc[2] * inv) << 32) | ((ull)bfb(acc[3] * inv) << 48);
                if (s == 0) *(ull*)(qb + c * 32 + g * 8) = pk;
                else        *(ull*)(kb + c * 32 + g * 8) = pk;
            } else {
#pragma unroll
                for (int r = 0; r < 4; ++r) {
                    int dd = 4 * g + r;
                    float vv = (dd == 10) ? 1.0f : acc[r];   // ones-row for row sums
                    *(__hip_bfloat16*)(vb + dd * 512 + c * 2) = __float2bfloat16(vv);
                }
            }
        }
    }
}

// ---------------- Kernel 2b: attention per (b,h): 4 waves x 64 c-rows (R9) ----
__global__ __launch_bounds__(256, 5) void attn2_kernel(const char* qin,          // aliases out2!
                                                       const char* __restrict__ kbufc,
                                                       const char* __restrict__ vbufc,
                                                       const float* __restrict__ btT,
                                                       unsigned int* out2)       // aliases qin!
{
    __shared__ __align__(16) char smem[32768];   // PT4[768] float4 (12KB) + Ps[4][64][40] bf16 (20KB)
    const int tid = threadIdx.x;
    const int b = blockIdx.x >> 3, h = blockIdx.x & 7;
    const int lane = tid & 63, w = tid >> 6;
    const int g = lane >> 4, m = lane & 15;
    const int rows0 = w * 64;

    // reversed bias table as float4: PT4[i] = (btr[i], btr[i+1], btr[i+3], btr[i+4]),
    // btr[i] = btT[h][764-i]. One ds_read_b128 delivers a whole C-operand bias.
    float4* PT4 = (float4*)smem;
    {
        const float* bth = btT + h * TBL_R;
        for (int i = tid; i < 768; i += 256) {
            float x0 = (i <= 764) ? bth[764 - i] : 0.f;
            float x1 = (i <= 763) ? bth[763 - i] : 0.f;
            float x2 = (i <= 761) ? bth[761 - i] : 0.f;
            float x3 = (i <= 760) ? bth[760 - i] : 0.f;
            PT4[i] = make_float4(x0, x1, x2, x3);
        }
    }
    char* PsB = smem + 12288 + w * 5120;

    const char* qb = qin + ((size_t)b * 80 + h * 10) * 1024;
    const char* kb = kbufc + ((size_t)b * 8 + h) * 8192;
    const char* vb = vbufc + ((size_t)b * 8 + h) * 8192;

    bf16x8 zf;
#pragma unroll
    for (int i = 0; i < 8; ++i) zf[i] = (__bf16)0.0f;
    const f32x4 zacc = {0.f, 0.f, 0.f, 0.f};

    bf16x8 qf[4];
#pragma unroll
    for (int t = 0; t < 4; ++t) {
        bf16x8 f = zf;
        if (lane < 32) f = *(const bf16x8*)(qb + (rows0 + t * 16 + m) * 32 + g * 16);
        qf[t] = f;
    }
    // Q aliases out2 (this block later overwrites bytes that alias other waves'
    // Q rows). __syncthreads does NOT drain register-destination global loads —
    // force completion of the Q loads before the barrier:
    asm volatile("s_waitcnt vmcnt(0)" ::: "memory");
    __syncthreads();   // PT4 ready; all waves' Q safely in registers

    // table bases; per (e0i,et): one b128 at base + 48*e0i + 24*et
    const int lane_cpart = 382 - 3 * (m >> 1) - (m & 1) + 6 * g;
    const float4* ptp[4];
#pragma unroll
    for (int t = 0; t < 4; ++t)
        ptp[t] = PT4 + (lane_cpart - 3 * ((rows0 + t * 16) >> 1));

    f32x4 Oacc[4];
#pragma unroll
    for (int t = 0; t < 4; ++t) Oacc[t] = zacc;

#pragma unroll
    for (int e0i = 0; e0i < 8; ++e0i) {
        const int e0 = e0i * 32;
        bf16x8 kf[2];
#pragma unroll
        for (int et = 0; et < 2; ++et) {
            bf16x8 f = zf;
            if (lane < 32) f = *(const bf16x8*)(kb + (e0 + et * 16 + m) * 32 + g * 16);
            kf[et] = f;
        }
        // S^T tiles with bias in the C-operand: D = K·Q(*log2e) + bias -> exp2 input
#pragma unroll
        for (int et = 0; et < 2; ++et) {
#pragma unroll
            for (int t = 0; t < 4; ++t) {
                float4 bq = ptp[t][48 * e0i + 24 * et];
                f32x4 biasC = {bq.x, bq.y, bq.z, bq.w};
                f32x4 st = __builtin_amdgcn_mfma_f32_16x16x32_bf16(kf[et], qf[t], biasC, 0, 0, 0);
                unsigned int w0 = cvtpk(vexp2(st[0]), vexp2(st[1]));
                unsigned int w1 = cvtpk(vexp2(st[2]), vexp2(st[3]));
                *(ull*)(PsB + (t * 16 + m) * 80 + et * 32 + g * 8) =
                    (ull)w0 | ((ull)w1 << 32);
            }
        }
        bf16x8 vf = *(const bf16x8*)(vb + m * 512 + e0 * 2 + g * 16);
#pragma unroll
        for (int t = 0; t < 4; ++t) {
            bf16x8 pf = *(const bf16x8*)(PsB + (t * 16 + m) * 80 + g * 16);
            Oacc[t] = __builtin_amdgcn_mfma_f32_16x16x32_bf16(pf, vf, Oacc[t], 0, 0, 0);
        }
    }

    // row sums live in output column d=10
    float rinv[4][4];
#pragma unroll
    for (int t = 0; t < 4; ++t)
#pragma unroll
        for (int r = 0; r < 4; ++r)
            rinv[t][r] = 1.f / __shfl(Oacc[t][r], (lane & 48) + 10, 64);

    if (m < 10) {
        unsigned int* op = out2 + ((size_t)b * 80 + h * 10 + m) * 256;
#pragma unroll
        for (int t = 0; t < 4; ++t) {
            unsigned int wd[4];
#pragma unroll
            for (int r = 0; r < 4; ++r) {
                float v = Oacc[t][r] * rinv[t][r];
                unsigned short hi = (unsigned short)bfb(v);
                float lo = v - bf2f(hi);
                wd[r] = (unsigned int)hi | (bfb(lo) << 16);
            }
            *(uint4*)(op + rows0 + t * 16 + 4 * g) = make_uint4(wd[0], wd[1], wd[2], wd[3]);
        }
    }
}

// ---------------- Fallback: fused mega (unchanged, self-consistent) -----------
#define XS_OFF 0
#define QH_OFF 53248
#define KH_OFF 69632
#define VT_OFF 94208
#define PS_OFF 111104
#define WL_OFF PS_OFF
#define BT_OFF 152064
#define SMEM_TOT 158208

__global__ __launch_bounds__(512, 2) void mega_kernel(const float* __restrict__ x,
                                                      const float* __restrict__ w_qkv,
                                                      const float* __restrict__ q_bias,
                                                      const float* __restrict__ v_bias,
                                                      const float* __restrict__ btT,
                                                      unsigned int* __restrict__ out2)
{
    __shared__ __align__(16) char smem[SMEM_TOT];
    const int tid = threadIdx.x;
    const int b = blockIdx.x;
    const int lane = tid & 63, w = tid >> 6;
    const int g = lane >> 4, m = lane & 15;

    bf16x8 zf;
#pragma unroll
    for (int i = 0; i < 8; ++i) zf[i] = (__bf16)0.0f;
    const f32x4 zacc = {0.f, 0.f, 0.f, 0.f};

    {
        const float* xb = x + (size_t)b * (N_TOK * C_CH);
        for (int u = tid; u < 10240; u += 512) {
            int np = u >> 8, c = u & 255;
            float a0 = xb[(2 * np) * C_CH + c];
            float a1 = xb[(2 * np + 1) * C_CH + c];
            *(unsigned int*)(smem + XS_OFF + c * 208 + np * 4) = bfb(a0) | (bfb(a1) << 16);
        }
        for (int u = tid; u < 2048; u += 512) {
            int c = u >> 3, np = u & 7;
            *(unsigned int*)(smem + XS_OFF + c * 208 + 160 + np * 4) = 0u;
        }
    }

    for (int hg = 0; hg < 4; ++hg) {
        __syncthreads();

        for (int u = tid; u < 96 * 52; u += 512) {
            int ri = u / 52, np = u - ri * 52;
            int m_ = ri & 15, sh = ri >> 4;
            unsigned int val = 0u;
            if (m_ < 10 && np < 40) {
                int s = sh >> 1, hl = sh & 1;
                const float* wr = w_qkv + ((s * 80) + (hg * 2 + hl) * 10 + m_) * 80 + 2 * np;
                val = bfb(wr[0]) | (bfb(wr[1]) << 16);
            }
            *(unsigned int*)(smem + WL_OFF + ri * 208 + np * 4) = val;
        }
        for (int i = tid; i < 2 * TBL_R; i += 512) {
            int hl = (i >= TBL_R) ? 1 : 0;
            int r = i - hl * TBL_R;
            *(float*)(smem + BT_OFF + (hl * 768 + r) * 4) =
                btT[(hg * 2 + hl) * TBL_R + (764 - r)];
        }
        __syncthreads();

        for (int sh = 0; sh < 6; ++sh) {
            int s = sh >> 1, hl = sh & 1, h = hg * 2 + hl;
            const char* wrow = smem + WL_OFF + (sh * 16 + m) * 208;
            bf16x8 af[3];
#pragma unroll
            for (int ks = 0; ks < 3; ++ks)
                af[ks] = *(const bf16x8*)(wrow + ks * 64 + g * 16);
            float bias_r[4];
#pragma unroll
            for (int r = 0; r < 4; ++r) {
                int dd = 4 * g + r;
                float bv = 0.f;
                if (dd < 10) {
                    if (s == 0) bv = q_bias[h * 10 + dd];
                    else if (s == 2) bv = v_bias[h * 10 + dd];
                }
                bias_r[r] = bv;
            }
#pragma unroll
            for (int ct2 = 0; ct2 < 2; ++ct2) {
                int ct = w + ct2 * 8;
                f32x4 acc = zacc;
#pragma unroll
                for (int ks = 0; ks < 3; ++ks) {
                    bf16x8 bfr = *(const bf16x8*)(smem + XS_OFF + (16 * ct + m) * 208 + ks * 64 + g * 16);
                    acc = __builtin_amdgcn_mfma_f32_16x16x32_bf16(af[ks], bfr, acc, 0, 0, 0);
                }
                int c = 16 * ct + m;
#pragma unroll
                for (int r = 0; r < 4; ++r) acc[r] += bias_r[r];
                if (s < 2) {
                    float ss = acc[0]*acc[0] + acc[1]*acc[1] + acc[2]*acc[2] + acc[3]*acc[3];
                    ss += __shfl_xor(ss, 16);
                    ss += __shfl_xor(ss, 32);
                    float inv = 1.f / (sqrtf(ss) + EPS_);
                    ull pk = (ull)bfb(acc[0] * inv) | ((ull)bfb(acc[1] * inv) << 16)
                           | ((ull)bfb(acc[2] * inv) << 32) | ((ull)bfb(acc[3] * inv) << 48);
                    if (s == 0) *(ull*)(smem + QH_OFF + (hl * 256 + c) * 32 + g * 8) = pk;
                    else        *(ull*)(smem + KH_OFF + (hl * 256 + c) * 48 + g * 8) = pk;
                } else {
#pragma unroll
                    for (int r = 0; r < 4; ++r) {
                        int dd = 4 * g + r;
                        float vv = acc[r];
                        if (r == 2) vv = (g == 2) ? 1.0f : vv;
                        *(__hip_bfloat16*)(smem + VT_OFF + (hl * 16 + dd) * 528 + c * 2) =
                            __float2bfloat16(vv);
                    }
                }
            }
        }
        __syncthreads();

        const int hl2 = w >> 2, h2 = hg * 2 + hl2;
        const int rows0 = (w & 3) * 64;
        const char* QhB = smem + QH_OFF + hl2 * (256 * 32);
        const char* KhB = smem + KH_OFF + hl2 * (256 * 48);
        const char* VtB = smem + VT_OFF + hl2 * (16 * 528);
        const float* btl = (const float*)(smem + BT_OFF) + hl2 * 768;
        char* PsB = smem + PS_OFF + w * 5120;

        bf16x8 qf[4];
#pragma unroll
        for (int t = 0; t < 4; ++t) {
            bf16x8 f = zf;
            if (lane < 32) f = *(const bf16x8*)(QhB + (rows0 + t * 16 + m) * 32 + g * 16);
            qf[t] = f;
        }
        const int lane_cpart = 382 - 3 * (m >> 1) - (m & 1) + 6 * g;
        const float* btp[4];
#pragma unroll
        for (int t = 0; t < 4; ++t)
            btp[t] = btl + (lane_cpart - 3 * ((rows0 + t * 16) >> 1));

        f32x4 Oacc[4];
#pragma unroll
        for (int t = 0; t < 4; ++t) Oacc[t] = zacc;

#pragma unroll
        for (int e0i = 0; e0i < 8; ++e0i) {
            const int e0 = e0i * 32;
            bf16x8 kf[2];
#pragma unroll
            for (int et = 0; et < 2; ++et) {
                bf16x8 f = zf;
                if (lane < 32) f = *(const bf16x8*)(KhB + (e0 + et * 16 + m) * 48 + g * 16);
                kf[et] = f;
            }
            f32x4 st[2][4];
#pragma unroll
            for (int et = 0; et < 2; ++et)
#pragma unroll
                for (int t = 0; t < 4; ++t)
                    st[et][t] = __builtin_amdgcn_mfma_f32_16x16x32_bf16(kf[et], qf[t], zacc, 0, 0, 0);
#pragma unroll
            for (int et = 0; et < 2; ++et) {
#pragma unroll
                for (int t = 0; t < 4; ++t) {
                    const float* bp = btp[t] + 48 * e0i + 24 * et;
                    float p0 = exp2f(fmaf(st[et][t][0], L2E, bp[0]));
                    float p1 = exp2f(fmaf(st[et][t][1], L2E, bp[1]));
                    float p2 = exp2f(fmaf(st[et][t][2], L2E, bp[3]));
                    float p3 = exp2f(fmaf(st[et][t][3], L2E, bp[4]));
                    unsigned int w0 = cvtpk(p0, p1);
                    unsigned int w1 = cvtpk(p2, p3);
                    *(ull*)(PsB + (t * 16 + m) * 80 + et * 32 + g * 8) =
                        (ull)w0 | ((ull)w1 << 32);
                }
            }
            bf16x8 vf = *(const bf16x8*)(VtB + m * 528 + e0 * 2 + g * 16);
#pragma unroll
            for (int t = 0; t < 4; ++t) {
                bf16x8 pf = *(const bf16x8*)(PsB + (t * 16 + m) * 80 + g * 16);
                Oacc[t] = __builtin_amdgcn_mfma_f32_16x16x32_bf16(pf, vf, Oacc[t], 0, 0, 0);
            }
        }

        float rinv[4][4];
#pragma unroll
        for (int t = 0; t < 4; ++t)
#pragma unroll
            for (int r = 0; r < 4; ++r)
                rinv[t][r] = 1.f / __shfl(Oacc[t][r], (lane & 48) + 10, 64);

        if (m < 10) {
            unsigned int* op = out2 + ((size_t)b * 80 + h2 * 10 + m) * 256;
#pragma unroll
            for (int t = 0; t < 4; ++t) {
                unsigned int wd[4];
#pragma unroll
                for (int r = 0; r < 4; ++r) {
                    float v = Oacc[t][r] * rinv[t][r];
                    unsigned short hi = (unsigned short)bfb(v);
                    float lo = v - bf2f(hi);
                    wd[r] = (unsigned int)hi | (bfb(lo) << 16);
                }
                *(uint4*)(op + rows0 + t * 16 + 4 * g) =
                    make_uint4(wd[0], wd[1], wd[2], wd[3]);
            }
        }
    }
}

// ---------------- Kernel 3: proj MFMA per (b, c-half), in-place safe (R9) -----
__global__ __launch_bounds__(512, 2) void proj_kernel2(const unsigned int* __restrict__ out2,
                                                       const float* __restrict__ proj_w,
                                                       const float* __restrict__ proj_b,
                                                       float* __restrict__ out)
{
    __shared__ __align__(16) char smem[69888];  // Blds[128][336] + Wdup[80][336]
    const int tid = threadIdx.x;
    const int b = blockIdx.x >> 1, ch = blockIdx.x & 1;
    const int lane = tid & 63, w = tid >> 6;
    const int g = lane >> 4, m = lane & 15;

    const unsigned int* src = out2 + (size_t)b * (80 * 256) + ch * 128;
    for (int u = tid; u < 80 * 128; u += 512) {
        int n = u >> 7, cl = u & 127;
        *(unsigned int*)(smem + cl * 336 + n * 4) = src[n * 256 + cl];
    }
    for (int u = tid; u < 6400; u += 512) {
        int no = u / 80, n = u - no * 80;
        unsigned int wb = bfb(proj_w[u]);
        *(unsigned int*)(smem + 43008 + no * 336 + n * 4) = wb | (wb << 16);
    }
    __syncthreads();

    const f32x4 zacc = {0.f, 0.f, 0.f, 0.f};
    for (int tt = w; tt < 40; tt += 8) {
        int nt = tt >> 3, ct = tt & 7;
        f32x4 acc = zacc;
#pragma unroll
        for (int ks = 0; ks < 5; ++ks) {
            bf16x8 afr = *(const bf16x8*)(smem + 43008 + (nt * 16 + m) * 336 + ks * 64 + g * 16);
            bf16x8 bfr = *(const bf16x8*)(smem + (16 * ct + m) * 336 + ks * 64 + g * 16);
            acc = __builtin_amdgcn_mfma_f32_16x16x32_bf16(afr, bfr, acc, 0, 0, 0);
        }
        int cc = ch * 128 + 16 * ct + m;
        float* dst = out + (size_t)b * (80 * 256) + cc;
#pragma unroll
        for (int r = 0; r < 4; ++r) {
            int no = nt * 16 + 4 * g + r;
            dst[no * 256] = acc[r] + proj_b[no];
        }
    }
}

extern "C" void kernel_launch(void* const* d_in, const int* in_sizes, int n_in,
                              void* d_out, int out_size, void* d_ws, size_t ws_size,
                              hipStream_t stream) {
    const float* x        = (const float*)d_in[0];
    const float* w_qkv    = (const float*)d_in[1];
    const float* q_bias   = (const float*)d_in[2];
    const float* v_bias   = (const float*)d_in[3];
    const float* w1       = (const float*)d_in[4];
    const float* b1       = (const float*)d_in[5];
    const float* w2       = (const float*)d_in[6];
    const float* proj_w   = (const float*)d_in[7];
    const float* proj_b   = (const float*)d_in[8];
    const float* table    = (const float*)d_in[9];
    float* out = (float*)d_out;

    float* btT = (float*)d_ws;   // [8][765] f32 @ ws+0 (32KB slot)

    const size_t NEED = 32768ULL + 2ULL * 16777216ULL;  // btT + K(16MB) + V(16MB)
    if (ws_size >= NEED) {
        char* kbufc = (char*)d_ws + 32768;
        char* vbufc = kbufc + 16777216;
        // qkv blocks 0..255 + fused CPB blocks 256..351 (btT ready before attn2)
        qkv_kernel<<<B_SZ + 96, 512, 0, stream>>>(x, w_qkv, q_bias, v_bias,
                                                  table, w1, b1, w2,
                                                  (char*)d_out, kbufc, vbufc, btT);
        attn2_kernel<<<B_SZ * 8, 256, 0, stream>>>((const char*)d_out, kbufc, vbufc,
                                                   btT, (unsigned int*)d_out);
    } else {
        cpb_kernel<<<TBL_R, 64, 0, stream>>>(table, w1, b1, w2, btT);
        mega_kernel<<<B_SZ, 512, 0, stream>>>(x, w_qkv, q_bias, v_bias, btT,
                                              (unsigned int*)d_out);
    }
    proj_kernel2<<<B_SZ * 2, 512, 0, stream>>>((const unsigned int*)d_out,
                                               proj_w, proj_b, out);
}